// Round 13
// baseline (418.712 us; speedup 1.0000x reference)
//
#include <hip/hip_runtime.h>
#include <hip/hip_bf16.h>

// MHA: B=1, S=4096, D=768, H=12, DK=64.
// Round 13:
//  - attention: wave q-tile 64 rows (qt=4), block = 256 q-rows, SEG=4,
//    grid (16,12,4)=768 = 3 blocks/CU. PV interleaved per key-slice (nt) so
//    pfrag registers stay small. MFMA/wave-iter doubles vs R12 at constant
//    LDS+staging cost.
//  - GEMMs: reverted to R10-proven 128x128 tiles (576 + 192 blocks).
// ws: Wt[4DD] | Qp,Kp,Vpt[3SD] | qh,kh,vh->Opart[4SD] | lsum f32[4*H*S];
//     Ctx aliases Qp.

constexpr int S_LEN = 4096;
constexpr int D_MODEL = 768;
constexpr int N_HEADS = 12;
constexpr int D_HEAD = 64;
constexpr int SEG = 4;
constexpr int SEG_LEN = S_LEN / SEG;   // 1024

// Q pre-scale: (1/sqrt(64)) * log2(e)  -> scores in exp2 domain
#define QSCALE 0.180336880111120f

typedef _Float16 f16;
typedef __attribute__((ext_vector_type(8))) _Float16 f16x8;
typedef __attribute__((ext_vector_type(4))) _Float16 f16x4;
typedef __attribute__((ext_vector_type(4))) float f32x4;

// ---------------------------------------------------------------------------
// Merged prep: blocks [0, 4608) = f32->f16 convert of q,k,v (8 elem/thread);
//              blocks [4608, 5184) = W transpose+convert (144 blocks per W).
// ---------------------------------------------------------------------------
__global__ __launch_bounds__(256) void prep_kernel(
    const float* __restrict__ q, const float* __restrict__ k,
    const float* __restrict__ v, f16* __restrict__ qh,
    f16* __restrict__ kh, f16* __restrict__ vh,
    const float* __restrict__ W0, const float* __restrict__ W1,
    const float* __restrict__ W2, const float* __restrict__ W3,
    f16* __restrict__ WtBase)
{
    __shared__ float T[64][65];
    int bid = blockIdx.x;
    const int t = threadIdx.x;
    if (bid < 4608) {
        int g = bid / 1536, r = bid % 1536;
        const float* x = (g == 0) ? q : (g == 1) ? k : v;
        f16* y = (g == 0) ? qh : (g == 1) ? kh : vh;
        int i = (r * 256 + t) * 8;
        float4 a = *(const float4*)&x[i];
        float4 b = *(const float4*)&x[i + 4];
        f16x8 h = { (f16)a.x, (f16)a.y, (f16)a.z, (f16)a.w,
                    (f16)b.x, (f16)b.y, (f16)b.z, (f16)b.w };
        *(f16x8*)&y[i] = h;
        return;
    }
    bid -= 4608;
    int g = bid / 144, r = bid % 144;
    const float* W = (g == 0) ? W0 : (g == 1) ? W1 : (g == 2) ? W2 : W3;
    f16* Wt = WtBase + (size_t)g * D_MODEL * D_MODEL;
    const int r0 = (r / 12) * 64;
    const int c0 = (r % 12) * 64;
    #pragma unroll
    for (int i = 0; i < 16; ++i) {
        int e = t + 256 * i; int rr = e >> 6, cc = e & 63;
        T[rr][cc] = W[(size_t)(r0 + rr) * D_MODEL + c0 + cc];
    }
    __syncthreads();
    #pragma unroll
    for (int i = 0; i < 16; ++i) {
        int e = t + 256 * i; int rr = e >> 6, cc = e & 63;
        Wt[(size_t)(c0 + rr) * D_MODEL + r0 + cc] = (f16)T[cc][rr];
    }
}

// ---------------------------------------------------------------------------
// 128x128 GEMM core with register-prefetch pipeline (R10-proven).
// Both operands k-contiguous (B^T form), BK=64. 4 waves 2x2; wave tile 64x64.
// LDS stride 72 f16.
// ---------------------------------------------------------------------------
#define GSTR 72

__device__ __forceinline__ void gemm128_core(
    const f16* __restrict__ A, const f16* __restrict__ B,
    f16* As, f16* Bs, int K, int row0, int col0, int t, f32x4 acc[4][4])
{
    const int w = t >> 6, l = t & 63, quad = l >> 4, l15 = l & 15;
    const int wm = (w & 1) * 64, wn = (w >> 1) * 64;

    f16x8 pa[4], pb[4];
    #pragma unroll
    for (int i = 0; i < 4; ++i) {
        int idx = i * 256 + t;
        int r = idx >> 3, c = (idx & 7) * 8;
        pa[i] = *(const f16x8*)&A[(size_t)(row0 + r) * K + c];
        pb[i] = *(const f16x8*)&B[(size_t)(col0 + r) * K + c];
    }

    for (int k0 = 0; k0 < K; k0 += 64) {
        __syncthreads();
        #pragma unroll
        for (int i = 0; i < 4; ++i) {
            int idx = i * 256 + t;
            int r = idx >> 3, c = (idx & 7) * 8;
            *(f16x8*)&As[r * GSTR + c] = pa[i];
            *(f16x8*)&Bs[r * GSTR + c] = pb[i];
        }
        __syncthreads();

        int kn = k0 + 64;
        if (kn < K) {
            #pragma unroll
            for (int i = 0; i < 4; ++i) {
                int idx = i * 256 + t;
                int r = idx >> 3, c = (idx & 7) * 8;
                pa[i] = *(const f16x8*)&A[(size_t)(row0 + r) * K + kn + c];
                pb[i] = *(const f16x8*)&B[(size_t)(col0 + r) * K + kn + c];
            }
        }

        #pragma unroll
        for (int kc = 0; kc < 2; ++kc) {
            f16x8 af[4], bf[4];
            #pragma unroll
            for (int mt = 0; mt < 4; ++mt)
                af[mt] = *(f16x8*)&As[(wm + mt * 16 + l15) * GSTR + kc * 32 + quad * 8];
            #pragma unroll
            for (int nt = 0; nt < 4; ++nt)
                bf[nt] = *(f16x8*)&Bs[(wn + nt * 16 + l15) * GSTR + kc * 32 + quad * 8];
            #pragma unroll
            for (int mt = 0; mt < 4; ++mt)
                #pragma unroll
                for (int nt = 0; nt < 4; ++nt)
                    acc[mt][nt] = __builtin_amdgcn_mfma_f32_16x16x32_f16(
                        af[mt], bf[nt], acc[mt][nt], 0, 0, 0);
        }
    }
}

// ---------------------------------------------------------------------------
// Batched QKV projections (f16 inputs), 128x128 tiles, 192 blocks per GEMM:
//  g0: Qp=(qh@Wtq^T+bq)*QSCALE [SxD]; g1: Kp [SxD]; g2: Vpt=Wtv@vh^T+bv [DxS].
// ---------------------------------------------------------------------------
__global__ __launch_bounds__(256) void qkv_gemm_kernel(
    const f16* __restrict__ qh, const f16* __restrict__ kh,
    const f16* __restrict__ vh, const f16* __restrict__ WtBase,
    const float* __restrict__ bq, const float* __restrict__ bk,
    const float* __restrict__ bv,
    f16* __restrict__ Qp, f16* __restrict__ Kp, f16* __restrict__ Vpt)
{
    __shared__ f16 As[128 * GSTR];
    __shared__ f16 Bs[128 * GSTR];
    const size_t DD = (size_t)D_MODEL * D_MODEL;
    int bid = blockIdx.x;
    int g = bid / 192, r = bid % 192;

    const f16 *A, *B; const float* bias; f16* Y;
    int N; bool biasRow; float scale;
    int row0, col0;
    if (g == 0) {
        A = qh; B = WtBase; bias = bq; Y = Qp;
        N = D_MODEL; biasRow = false; scale = QSCALE;
        row0 = (r / 6) * 128; col0 = (r % 6) * 128;
    } else if (g == 1) {
        A = kh; B = WtBase + DD; bias = bk; Y = Kp;
        N = D_MODEL; biasRow = false; scale = 1.0f;
        row0 = (r / 6) * 128; col0 = (r % 6) * 128;
    } else {
        A = WtBase + 2 * DD; B = vh; bias = bv; Y = Vpt;
        N = S_LEN; biasRow = true; scale = 1.0f;
        row0 = (r / 32) * 128; col0 = (r % 32) * 128;
    }

    f32x4 acc[4][4];
    #pragma unroll
    for (int i = 0; i < 4; ++i)
        #pragma unroll
        for (int j = 0; j < 4; ++j) acc[i][j] = (f32x4){0.f, 0.f, 0.f, 0.f};

    const int t = threadIdx.x;
    gemm128_core(A, B, As, Bs, D_MODEL, row0, col0, t, acc);

    const int w = t >> 6, l = t & 63, quad = l >> 4, l15 = l & 15;
    const int wm = (w & 1) * 64, wn = (w >> 1) * 64;
    #pragma unroll
    for (int mt = 0; mt < 4; ++mt) {
        #pragma unroll
        for (int nt = 0; nt < 4; ++nt) {
            int col = col0 + wn + nt * 16 + l15;
            #pragma unroll
            for (int reg = 0; reg < 4; ++reg) {
                int row = row0 + wm + mt * 16 + quad * 4 + reg;
                float b = biasRow ? bias[row] : bias[col];
                Y[(size_t)row * N + col] = (f16)((acc[mt][nt][reg] + b) * scale);
            }
        }
    }
}

// ---------------------------------------------------------------------------
// Flash attention, transposed-score form, P in registers, qt=4.
// Block = (256 q-rows, head, segment); 4 waves x 64 q-rows. SEG=4.
// Per k-tile (64 keys): S^T = K@Q^T (K=32), exp2 -> pfrag (f16x4, B-operand
// of K=16 PV), PV interleaved per key-slice nt: ctx^T += Vt(A) * P^T(B).
// ---------------------------------------------------------------------------
#define LSTR 72

__global__ __launch_bounds__(256, 3) void flash_attn_part_kernel(
    const f16* __restrict__ Q, const f16* __restrict__ K,
    const f16* __restrict__ Vg, f16* __restrict__ Opart,
    float* __restrict__ lsum)
{
    __shared__ f16 Ks[64 * LSTR];
    __shared__ f16 Vt[64 * LSTR];

    const int t    = threadIdx.x;
    const int w    = t >> 6;
    const int l    = t & 63;
    const int quad = l >> 4;
    const int l15  = l & 15;
    const int h    = blockIdx.y;
    const int q0   = blockIdx.x * 256;
    const int seg  = blockIdx.z;
    const int c0   = h * D_HEAD;
    const size_t SD = (size_t)S_LEN * D_MODEL;

    // Q fragments (B-operand for S^T), 4 q-tiles of 16, direct from global
    f16x8 qa[4][2];
    #pragma unroll
    for (int qt = 0; qt < 4; ++qt) {
        const f16* qrow = Q + (size_t)(q0 + w * 64 + qt * 16 + l15) * D_MODEL + c0;
        qa[qt][0] = *(const f16x8*)&qrow[quad * 8];
        qa[qt][1] = *(const f16x8*)&qrow[32 + quad * 8];
    }

    f32x4 ctx[4][4];          // [q-tile][dv-tile], C rows = dv, cols = q
    float lAcc[4] = {0.f, 0.f, 0.f, 0.f};
    #pragma unroll
    for (int qt = 0; qt < 4; ++qt)
        #pragma unroll
        for (int i = 0; i < 4; ++i) ctx[qt][i] = (f32x4){0.f, 0.f, 0.f, 0.f};

    const int kt0 = seg * SEG_LEN;

    f16x8 kreg[2], vreg[2];
    #pragma unroll
    for (int i = 0; i < 2; ++i) {
        int idx = i * 256 + t;
        int r = idx >> 3, c = (idx & 7) * 8;
        kreg[i] = *(const f16x8*)&K[(size_t)(kt0 + r) * D_MODEL + c0 + c];
        vreg[i] = *(const f16x8*)&Vg[(size_t)(c0 + r) * S_LEN + kt0 + c];
    }

    for (int kt = kt0; kt < kt0 + SEG_LEN; kt += 64) {
        __syncthreads();
        #pragma unroll
        for (int i = 0; i < 2; ++i) {
            int idx = i * 256 + t;
            int r = idx >> 3, c = (idx & 7) * 8;
            *(f16x8*)&Ks[r * LSTR + c] = kreg[i];
            *(f16x8*)&Vt[r * LSTR + c] = vreg[i];
        }
        __syncthreads();

        int ktn = kt + 64;
        if (ktn < kt0 + SEG_LEN) {
            #pragma unroll
            for (int i = 0; i < 2; ++i) {
                int idx = i * 256 + t;
                int r = idx >> 3, c = (idx & 7) * 8;
                kreg[i] = *(const f16x8*)&K[(size_t)(ktn + r) * D_MODEL + c0 + c];
                vreg[i] = *(const f16x8*)&Vg[(size_t)(c0 + r) * S_LEN + ktn + c];
            }
        }

        // per key-slice: scores -> exp -> immediate PV (pfrag short-lived)
        #pragma unroll
        for (int nt = 0; nt < 4; ++nt) {
            f16x8 kb0 = *(f16x8*)&Ks[(nt * 16 + l15) * LSTR + quad * 8];
            f16x8 kb1 = *(f16x8*)&Ks[(nt * 16 + l15) * LSTR + 32 + quad * 8];
            f16x4 pfrag[4];
            #pragma unroll
            for (int qt = 0; qt < 4; ++qt) {
                f32x4 z = (f32x4){0.f, 0.f, 0.f, 0.f};
                z = __builtin_amdgcn_mfma_f32_16x16x32_f16(kb0, qa[qt][0], z, 0, 0, 0);
                z = __builtin_amdgcn_mfma_f32_16x16x32_f16(kb1, qa[qt][1], z, 0, 0, 0);
                float p0 = __builtin_amdgcn_exp2f(z[0]);
                float p1 = __builtin_amdgcn_exp2f(z[1]);
                float p2 = __builtin_amdgcn_exp2f(z[2]);
                float p3 = __builtin_amdgcn_exp2f(z[3]);
                lAcc[qt] += (p0 + p1) + (p2 + p3);
                pfrag[qt] = (f16x4){ (f16)p0, (f16)p1, (f16)p2, (f16)p3 };
            }
            #pragma unroll
            for (int mt = 0; mt < 4; ++mt) {
                f16x4 va = *(f16x4*)&Vt[(mt * 16 + l15) * LSTR + nt * 16 + quad * 4];
                #pragma unroll
                for (int qt = 0; qt < 4; ++qt)
                    ctx[qt][mt] = __builtin_amdgcn_mfma_f32_16x16x16f16(
                        va, pfrag[qt], ctx[qt][mt], 0, 0, 0);
            }
        }
    }

    // ---- epilogue: ctx^T rows = dv (4 contiguous per reg-block) ----
    #pragma unroll
    for (int qt = 0; qt < 4; ++qt) {
        int qrow = q0 + w * 64 + qt * 16 + l15;
        #pragma unroll
        for (int mt = 0; mt < 4; ++mt) {
            f16x4 ov = { (f16)ctx[qt][mt][0], (f16)ctx[qt][mt][1],
                         (f16)ctx[qt][mt][2], (f16)ctx[qt][mt][3] };
            *(f16x4*)&Opart[(size_t)seg * SD + (size_t)qrow * D_MODEL
                            + c0 + mt * 16 + quad * 4] = ov;
        }
        float s = lAcc[qt];
        s += __shfl_xor(s, 16);
        s += __shfl_xor(s, 32);
        if (quad == 0)
            lsum[((size_t)seg * N_HEADS + h) * S_LEN + qrow] = s;
    }
}

// ---------------------------------------------------------------------------
// Combine 4 segments: Ctx = sum(O_s) / sum(l_s).  1536 blocks.
// ---------------------------------------------------------------------------
__global__ __launch_bounds__(256) void combine_kernel(
    const f16* __restrict__ Opart, const float* __restrict__ lsum,
    f16* __restrict__ Ctx)
{
    const size_t SD = (size_t)S_LEN * D_MODEL;
    int tid = blockIdx.x * 256 + threadIdx.x;
    int idx = tid * 8;
    int row = idx / D_MODEL;
    int c   = idx % D_MODEL;
    int h   = c >> 6;
    float lt = 0.f;
    #pragma unroll
    for (int s = 0; s < SEG; ++s)
        lt += lsum[((size_t)s * N_HEADS + h) * S_LEN + row];
    float inv = 1.0f / lt;
    float o[8] = {};
    #pragma unroll
    for (int s = 0; s < SEG; ++s) {
        f16x8 ov = *(const f16x8*)&Opart[(size_t)s * SD + (size_t)row * D_MODEL + c];
        #pragma unroll
        for (int j = 0; j < 8; ++j) o[j] += (float)ov[j];
    }
    f16x8 r;
    #pragma unroll
    for (int j = 0; j < 8; ++j) r[j] = (f16)(o[j] * inv);
    *(f16x8*)&Ctx[(size_t)row * D_MODEL + c] = r;
}

// ---------------------------------------------------------------------------
// O-projection: out_f32 = Ctx @ Wto^T + bo.  128x128 tiles, 192 blocks.
// ---------------------------------------------------------------------------
__global__ __launch_bounds__(256) void oproj_kernel(
    const f16* __restrict__ Ctx, const f16* __restrict__ Wto,
    const float* __restrict__ bo, float* __restrict__ out)
{
    __shared__ f16 As[128 * GSTR];
    __shared__ f16 Bs[128 * GSTR];
    int bid = blockIdx.x;
    int row0 = (bid / 6) * 128, col0 = (bid % 6) * 128;

    f32x4 acc[4][4];
    #pragma unroll
    for (int i = 0; i < 4; ++i)
        #pragma unroll
        for (int j = 0; j < 4; ++j) acc[i][j] = (f32x4){0.f, 0.f, 0.f, 0.f};

    const int t = threadIdx.x;
    gemm128_core(Ctx, Wto, As, Bs, D_MODEL, row0, col0, t, acc);

    const int w = t >> 6, l = t & 63, quad = l >> 4, l15 = l & 15;
    const int wm = (w & 1) * 64, wn = (w >> 1) * 64;
    #pragma unroll
    for (int mt = 0; mt < 4; ++mt) {
        #pragma unroll
        for (int nt = 0; nt < 4; ++nt) {
            int col = col0 + wn + nt * 16 + l15;
            float b = bo[col];
            #pragma unroll
            for (int reg = 0; reg < 4; ++reg) {
                int row = row0 + wm + mt * 16 + quad * 4 + reg;
                out[(size_t)row * D_MODEL + col] = acc[mt][nt][reg] + b;
            }
        }
    }
}

// ---------------------------------------------------------------------------
extern "C" void kernel_launch(void* const* d_in, const int* in_sizes, int n_in,
                              void* d_out, int out_size, void* d_ws, size_t ws_size,
                              hipStream_t stream)
{
    const float* q  = (const float*)d_in[0];
    const float* k  = (const float*)d_in[1];
    const float* v  = (const float*)d_in[2];
    const float* Wq = (const float*)d_in[3];
    const float* bq = (const float*)d_in[4];
    const float* Wk = (const float*)d_in[5];
    const float* bk = (const float*)d_in[6];
    const float* Wv = (const float*)d_in[7];
    const float* bv = (const float*)d_in[8];
    const float* Wo = (const float*)d_in[9];
    const float* bo = (const float*)d_in[10];
    float* out = (float*)d_out;

    const size_t SD = (size_t)S_LEN * D_MODEL;
    const size_t DD = (size_t)D_MODEL * D_MODEL;
    f16* base   = (f16*)d_ws;
    f16* WtBase = base;                  // Wtq|Wtk|Wtv|Wto (4*DD)
    f16* Wto    = WtBase + 3 * DD;
    f16* Qp     = base + 4 * DD;
    f16* Kp     = Qp + SD;
    f16* Vpt    = Kp + SD;               // [D][S]
    f16* qh     = Vpt + SD;              // 3SD staging region...
    f16* kh     = qh + SD;
    f16* vh     = kh + SD;
    f16* Opart  = qh;                    // ...reused: Opart = 4 contiguous SD
    float* lsum = (float*)(base + 4 * DD + 7 * SD);  // [SEG][H][S]
    f16* Ctx    = Qp;                    // Qp dead once combine runs

    prep_kernel<<<3 * 1536 + 4 * 144, 256, 0, stream>>>(
        q, k, v, qh, kh, vh, Wq, Wk, Wv, Wo, WtBase);

    qkv_gemm_kernel<<<3 * 192, 256, 0, stream>>>(
        qh, kh, vh, WtBase, bq, bk, bv, Qp, Kp, Vpt);

    dim3 gAttn(S_LEN / 256, N_HEADS, SEG);   // (16, 12, 4)
    flash_attn_part_kernel<<<gAttn, 256, 0, stream>>>(Qp, Kp, Vpt, Opart, lsum);

    combine_kernel<<<1536, 256, 0, stream>>>(Opart, lsum, Ctx);

    oproj_kernel<<<192, 256, 0, stream>>>(Ctx, Wto, bo, out);
}

// Round 14
// 223.054 us; speedup vs baseline: 1.8772x; 1.8772x over previous
//
#include <hip/hip_runtime.h>
#include <hip/hip_bf16.h>

// MHA: B=1, S=4096, D=768, H=12, DK=64.
// Round 14: R10 config (best measured: 225 us) + ping-pong K/V LDS in
//   attention: ONE barrier per k-iter (was 2); prefetch issued post-barrier
//   so global loads stay in flight through the whole next compute phase.
//   qt=2 (VGPR 64, no spill — R13's qt=4 spilled to scratch, 1.2 TB traffic).
// ws layout identical to R10.

constexpr int S_LEN = 4096;
constexpr int D_MODEL = 768;
constexpr int N_HEADS = 12;
constexpr int D_HEAD = 64;
constexpr int SEG = 2;
constexpr int SEG_LEN = S_LEN / SEG;   // 2048
constexpr int NITER = SEG_LEN / 64;    // 32

// Q pre-scale: (1/sqrt(64)) * log2(e)  -> scores in exp2 domain
#define QSCALE 0.180336880111120f

typedef _Float16 f16;
typedef __attribute__((ext_vector_type(8))) _Float16 f16x8;
typedef __attribute__((ext_vector_type(4))) _Float16 f16x4;
typedef __attribute__((ext_vector_type(4))) float f32x4;

// ---------------------------------------------------------------------------
// Merged prep: blocks [0, 4608) = f32->f16 convert of q,k,v (8 elem/thread);
//              blocks [4608, 5184) = W transpose+convert (144 blocks per W).
// ---------------------------------------------------------------------------
__global__ __launch_bounds__(256) void prep_kernel(
    const float* __restrict__ q, const float* __restrict__ k,
    const float* __restrict__ v, f16* __restrict__ qh,
    f16* __restrict__ kh, f16* __restrict__ vh,
    const float* __restrict__ W0, const float* __restrict__ W1,
    const float* __restrict__ W2, const float* __restrict__ W3,
    f16* __restrict__ WtBase)
{
    __shared__ float T[64][65];
    int bid = blockIdx.x;
    const int t = threadIdx.x;
    if (bid < 4608) {
        int g = bid / 1536, r = bid % 1536;
        const float* x = (g == 0) ? q : (g == 1) ? k : v;
        f16* y = (g == 0) ? qh : (g == 1) ? kh : vh;
        int i = (r * 256 + t) * 8;
        float4 a = *(const float4*)&x[i];
        float4 b = *(const float4*)&x[i + 4];
        f16x8 h = { (f16)a.x, (f16)a.y, (f16)a.z, (f16)a.w,
                    (f16)b.x, (f16)b.y, (f16)b.z, (f16)b.w };
        *(f16x8*)&y[i] = h;
        return;
    }
    bid -= 4608;
    int g = bid / 144, r = bid % 144;
    const float* W = (g == 0) ? W0 : (g == 1) ? W1 : (g == 2) ? W2 : W3;
    f16* Wt = WtBase + (size_t)g * D_MODEL * D_MODEL;
    const int r0 = (r / 12) * 64;
    const int c0 = (r % 12) * 64;
    #pragma unroll
    for (int i = 0; i < 16; ++i) {
        int e = t + 256 * i; int rr = e >> 6, cc = e & 63;
        T[rr][cc] = W[(size_t)(r0 + rr) * D_MODEL + c0 + cc];
    }
    __syncthreads();
    #pragma unroll
    for (int i = 0; i < 16; ++i) {
        int e = t + 256 * i; int rr = e >> 6, cc = e & 63;
        Wt[(size_t)(c0 + rr) * D_MODEL + r0 + cc] = (f16)T[cc][rr];
    }
}

// ---------------------------------------------------------------------------
// 128x128 GEMM core with register-prefetch pipeline (R10-proven, unchanged).
// Both operands k-contiguous (B^T form), BK=64. 4 waves 2x2; wave tile 64x64.
// LDS stride 72 f16.
// ---------------------------------------------------------------------------
#define GSTR 72

__device__ __forceinline__ void gemm128_core(
    const f16* __restrict__ A, const f16* __restrict__ B,
    f16* As, f16* Bs, int K, int row0, int col0, int t, f32x4 acc[4][4])
{
    const int w = t >> 6, l = t & 63, quad = l >> 4, l15 = l & 15;
    const int wm = (w & 1) * 64, wn = (w >> 1) * 64;

    f16x8 pa[4], pb[4];
    #pragma unroll
    for (int i = 0; i < 4; ++i) {
        int idx = i * 256 + t;
        int r = idx >> 3, c = (idx & 7) * 8;
        pa[i] = *(const f16x8*)&A[(size_t)(row0 + r) * K + c];
        pb[i] = *(const f16x8*)&B[(size_t)(col0 + r) * K + c];
    }

    for (int k0 = 0; k0 < K; k0 += 64) {
        __syncthreads();
        #pragma unroll
        for (int i = 0; i < 4; ++i) {
            int idx = i * 256 + t;
            int r = idx >> 3, c = (idx & 7) * 8;
            *(f16x8*)&As[r * GSTR + c] = pa[i];
            *(f16x8*)&Bs[r * GSTR + c] = pb[i];
        }
        __syncthreads();

        int kn = k0 + 64;
        if (kn < K) {
            #pragma unroll
            for (int i = 0; i < 4; ++i) {
                int idx = i * 256 + t;
                int r = idx >> 3, c = (idx & 7) * 8;
                pa[i] = *(const f16x8*)&A[(size_t)(row0 + r) * K + kn + c];
                pb[i] = *(const f16x8*)&B[(size_t)(col0 + r) * K + kn + c];
            }
        }

        #pragma unroll
        for (int kc = 0; kc < 2; ++kc) {
            f16x8 af[4], bf[4];
            #pragma unroll
            for (int mt = 0; mt < 4; ++mt)
                af[mt] = *(f16x8*)&As[(wm + mt * 16 + l15) * GSTR + kc * 32 + quad * 8];
            #pragma unroll
            for (int nt = 0; nt < 4; ++nt)
                bf[nt] = *(f16x8*)&Bs[(wn + nt * 16 + l15) * GSTR + kc * 32 + quad * 8];
            #pragma unroll
            for (int mt = 0; mt < 4; ++mt)
                #pragma unroll
                for (int nt = 0; nt < 4; ++nt)
                    acc[mt][nt] = __builtin_amdgcn_mfma_f32_16x16x32_f16(
                        af[mt], bf[nt], acc[mt][nt], 0, 0, 0);
        }
    }
}

// ---------------------------------------------------------------------------
// Batched QKV projections (f16 inputs), 128x128 tiles, 192 blocks per GEMM:
//  g0: Qp=(qh@Wtq^T+bq)*QSCALE [SxD]; g1: Kp [SxD]; g2: Vpt=Wtv@vh^T+bv [DxS].
// ---------------------------------------------------------------------------
__global__ __launch_bounds__(256) void qkv_gemm_kernel(
    const f16* __restrict__ qh, const f16* __restrict__ kh,
    const f16* __restrict__ vh, const f16* __restrict__ WtBase,
    const float* __restrict__ bq, const float* __restrict__ bk,
    const float* __restrict__ bv,
    f16* __restrict__ Qp, f16* __restrict__ Kp, f16* __restrict__ Vpt)
{
    __shared__ f16 As[128 * GSTR];
    __shared__ f16 Bs[128 * GSTR];
    const size_t DD = (size_t)D_MODEL * D_MODEL;
    int bid = blockIdx.x;
    int g = bid / 192, r = bid % 192;

    const f16 *A, *B; const float* bias; f16* Y;
    int N; bool biasRow; float scale;
    int row0, col0;
    if (g == 0) {
        A = qh; B = WtBase; bias = bq; Y = Qp;
        N = D_MODEL; biasRow = false; scale = QSCALE;
        row0 = (r / 6) * 128; col0 = (r % 6) * 128;
    } else if (g == 1) {
        A = kh; B = WtBase + DD; bias = bk; Y = Kp;
        N = D_MODEL; biasRow = false; scale = 1.0f;
        row0 = (r / 6) * 128; col0 = (r % 6) * 128;
    } else {
        A = WtBase + 2 * DD; B = vh; bias = bv; Y = Vpt;
        N = S_LEN; biasRow = true; scale = 1.0f;
        row0 = (r / 32) * 128; col0 = (r % 32) * 128;
    }

    f32x4 acc[4][4];
    #pragma unroll
    for (int i = 0; i < 4; ++i)
        #pragma unroll
        for (int j = 0; j < 4; ++j) acc[i][j] = (f32x4){0.f, 0.f, 0.f, 0.f};

    const int t = threadIdx.x;
    gemm128_core(A, B, As, Bs, D_MODEL, row0, col0, t, acc);

    const int w = t >> 6, l = t & 63, quad = l >> 4, l15 = l & 15;
    const int wm = (w & 1) * 64, wn = (w >> 1) * 64;
    #pragma unroll
    for (int mt = 0; mt < 4; ++mt) {
        #pragma unroll
        for (int nt = 0; nt < 4; ++nt) {
            int col = col0 + wn + nt * 16 + l15;
            #pragma unroll
            for (int reg = 0; reg < 4; ++reg) {
                int row = row0 + wm + mt * 16 + quad * 4 + reg;
                float b = biasRow ? bias[row] : bias[col];
                Y[(size_t)row * N + col] = (f16)((acc[mt][nt][reg] + b) * scale);
            }
        }
    }
}

// ---------------------------------------------------------------------------
// Flash attention, transposed-score form, P in registers, qt=2, SEG=2,
// ping-pong K/V LDS: one barrier per k-iter; prefetch issued post-barrier.
// Block = (128 q-rows, head, segment); 4 waves x 32 q-rows.
// ---------------------------------------------------------------------------
#define LSTR 72

__global__ __launch_bounds__(256, 4) void flash_attn_part_kernel(
    const f16* __restrict__ Q, const f16* __restrict__ K,
    const f16* __restrict__ Vg, f16* __restrict__ Opart,
    float* __restrict__ lsum)
{
    __shared__ f16 Ks[2][64 * LSTR];
    __shared__ f16 Vt[2][64 * LSTR];

    const int t    = threadIdx.x;
    const int w    = t >> 6;
    const int l    = t & 63;
    const int quad = l >> 4;
    const int l15  = l & 15;
    const int h    = blockIdx.y;
    const int q0   = blockIdx.x * 128;
    const int seg  = blockIdx.z;
    const int c0   = h * D_HEAD;
    const size_t SD = (size_t)S_LEN * D_MODEL;

    // staging coords (per thread, fixed)
    const int sr = t >> 3;            // row 0..31  (idx = i*256+t -> r = i*32+sr)
    const int sc = (t & 7) * 8;       // f16 col chunk

    // Q fragments (B-operand for S^T), direct from global, resident all loop
    f16x8 qa[2][2];
    #pragma unroll
    for (int qt = 0; qt < 2; ++qt) {
        const f16* qrow = Q + (size_t)(q0 + w * 32 + qt * 16 + l15) * D_MODEL + c0;
        qa[qt][0] = *(const f16x8*)&qrow[quad * 8];
        qa[qt][1] = *(const f16x8*)&qrow[32 + quad * 8];
    }

    f32x4 ctx[2][4];          // [q-tile][dv-tile], C rows = dv, cols = q
    float lAcc[2] = {0.f, 0.f};
    #pragma unroll
    for (int qt = 0; qt < 2; ++qt)
        #pragma unroll
        for (int i = 0; i < 4; ++i) ctx[qt][i] = (f32x4){0.f, 0.f, 0.f, 0.f};

    const int kt0 = seg * SEG_LEN;

    // ---- prologue: tile 0 -> buf 0; prefetch tile 1 after the barrier ----
    f16x8 kreg[2], vreg[2];
    #pragma unroll
    for (int i = 0; i < 2; ++i) {
        int r = i * 32 + sr;
        kreg[i] = *(const f16x8*)&K[(size_t)(kt0 + r) * D_MODEL + c0 + sc];
        vreg[i] = *(const f16x8*)&Vg[(size_t)(c0 + r) * S_LEN + kt0 + sc];
    }
    #pragma unroll
    for (int i = 0; i < 2; ++i) {
        int r = i * 32 + sr;
        *(f16x8*)&Ks[0][r * LSTR + sc] = kreg[i];
        *(f16x8*)&Vt[0][r * LSTR + sc] = vreg[i];
    }
    __syncthreads();
    #pragma unroll
    for (int i = 0; i < 2; ++i) {
        int r = i * 32 + sr;
        kreg[i] = *(const f16x8*)&K[(size_t)(kt0 + 64 + r) * D_MODEL + c0 + sc];
        vreg[i] = *(const f16x8*)&Vg[(size_t)(c0 + r) * S_LEN + kt0 + 64 + sc];
    }

    for (int it = 0; it < NITER; ++it) {
        const int buf = it & 1;
        const f16* ks = Ks[buf];
        const f16* vt = Vt[buf];

        // ---- compute on buf: S^T (K=32) -> exp2 -> pfrag -> PV (K=16) ----
        f16x4 pfrag[2][4];
        #pragma unroll
        for (int nt = 0; nt < 4; ++nt) {
            f16x8 kb0 = *(const f16x8*)&ks[(nt * 16 + l15) * LSTR + quad * 8];
            f16x8 kb1 = *(const f16x8*)&ks[(nt * 16 + l15) * LSTR + 32 + quad * 8];
            #pragma unroll
            for (int qt = 0; qt < 2; ++qt) {
                f32x4 z = (f32x4){0.f, 0.f, 0.f, 0.f};
                z = __builtin_amdgcn_mfma_f32_16x16x32_f16(kb0, qa[qt][0], z, 0, 0, 0);
                z = __builtin_amdgcn_mfma_f32_16x16x32_f16(kb1, qa[qt][1], z, 0, 0, 0);
                float p0 = __builtin_amdgcn_exp2f(z[0]);
                float p1 = __builtin_amdgcn_exp2f(z[1]);
                float p2 = __builtin_amdgcn_exp2f(z[2]);
                float p3 = __builtin_amdgcn_exp2f(z[3]);
                lAcc[qt] += (p0 + p1) + (p2 + p3);
                pfrag[qt][nt] = (f16x4){ (f16)p0, (f16)p1, (f16)p2, (f16)p3 };
            }
        }
        #pragma unroll
        for (int mt = 0; mt < 4; ++mt) {
            #pragma unroll
            for (int nt = 0; nt < 4; ++nt) {
                f16x4 va = *(const f16x4*)&vt[(mt * 16 + l15) * LSTR + nt * 16 + quad * 4];
                #pragma unroll
                for (int qt = 0; qt < 2; ++qt)
                    ctx[qt][mt] = __builtin_amdgcn_mfma_f32_16x16x16f16(
                        va, pfrag[qt][nt], ctx[qt][mt], 0, 0, 0);
            }
        }

        // ---- write tile it+1 into the other buffer (vmcnt wait lands here,
        //      a full compute phase after the loads were issued) ----
        if (it + 1 < NITER) {
            #pragma unroll
            for (int i = 0; i < 2; ++i) {
                int r = i * 32 + sr;
                *(f16x8*)&Ks[1 - buf][r * LSTR + sc] = kreg[i];
                *(f16x8*)&Vt[1 - buf][r * LSTR + sc] = vreg[i];
            }
        }
        __syncthreads();   // the ONLY barrier: orders this iter's reads/writes
                           // against next iter's writes/reads

        // ---- prefetch tile it+2 (post-barrier: stays in flight through the
        //      entire next compute phase) ----
        if (it + 2 < NITER) {
            int ktn = kt0 + (it + 2) * 64;
            #pragma unroll
            for (int i = 0; i < 2; ++i) {
                int r = i * 32 + sr;
                kreg[i] = *(const f16x8*)&K[(size_t)(ktn + r) * D_MODEL + c0 + sc];
                vreg[i] = *(const f16x8*)&Vg[(size_t)(c0 + r) * S_LEN + ktn + sc];
            }
        }
    }

    // ---- epilogue: ctx^T rows = dv (4 contiguous per reg-block) ----
    #pragma unroll
    for (int qt = 0; qt < 2; ++qt) {
        int qrow = q0 + w * 32 + qt * 16 + l15;
        #pragma unroll
        for (int mt = 0; mt < 4; ++mt) {
            f16x4 ov = { (f16)ctx[qt][mt][0], (f16)ctx[qt][mt][1],
                         (f16)ctx[qt][mt][2], (f16)ctx[qt][mt][3] };
            *(f16x4*)&Opart[(size_t)seg * SD + (size_t)qrow * D_MODEL
                            + c0 + mt * 16 + quad * 4] = ov;
        }
        float s = lAcc[qt];
        s += __shfl_xor(s, 16);
        s += __shfl_xor(s, 32);
        if (quad == 0)
            lsum[((size_t)seg * N_HEADS + h) * S_LEN + qrow] = s;
    }
}

// ---------------------------------------------------------------------------
// Combine 2 segments: Ctx = (O0 + O1) / (l0 + l1).  1536 blocks.
// ---------------------------------------------------------------------------
__global__ __launch_bounds__(256) void combine_kernel(
    const f16* __restrict__ Opart, const float* __restrict__ lsum,
    f16* __restrict__ Ctx)
{
    const size_t SD = (size_t)S_LEN * D_MODEL;
    int tid = blockIdx.x * 256 + threadIdx.x;
    int idx = tid * 8;
    int row = idx / D_MODEL;
    int c   = idx % D_MODEL;
    int h   = c >> 6;
    float l0 = lsum[(size_t)h * S_LEN + row];
    float l1 = lsum[((size_t)N_HEADS + h) * S_LEN + row];
    float inv = 1.0f / (l0 + l1);
    f16x8 o0 = *(const f16x8*)&Opart[(size_t)row * D_MODEL + c];
    f16x8 o1 = *(const f16x8*)&Opart[SD + (size_t)row * D_MODEL + c];
    f16x8 r;
    #pragma unroll
    for (int j = 0; j < 8; ++j)
        r[j] = (f16)(((float)o0[j] + (float)o1[j]) * inv);
    *(f16x8*)&Ctx[(size_t)row * D_MODEL + c] = r;
}

// ---------------------------------------------------------------------------
// O-projection: out_f32 = Ctx @ Wto^T + bo.  128x128 tiles, 192 blocks.
// ---------------------------------------------------------------------------
__global__ __launch_bounds__(256) void oproj_kernel(
    const f16* __restrict__ Ctx, const f16* __restrict__ Wto,
    const float* __restrict__ bo, float* __restrict__ out)
{
    __shared__ f16 As[128 * GSTR];
    __shared__ f16 Bs[128 * GSTR];
    int bid = blockIdx.x;
    int row0 = (bid / 6) * 128, col0 = (bid % 6) * 128;

    f32x4 acc[4][4];
    #pragma unroll
    for (int i = 0; i < 4; ++i)
        #pragma unroll
        for (int j = 0; j < 4; ++j) acc[i][j] = (f32x4){0.f, 0.f, 0.f, 0.f};

    const int t = threadIdx.x;
    gemm128_core(Ctx, Wto, As, Bs, D_MODEL, row0, col0, t, acc);

    const int w = t >> 6, l = t & 63, quad = l >> 4, l15 = l & 15;
    const int wm = (w & 1) * 64, wn = (w >> 1) * 64;
    #pragma unroll
    for (int mt = 0; mt < 4; ++mt) {
        #pragma unroll
        for (int nt = 0; nt < 4; ++nt) {
            int col = col0 + wn + nt * 16 + l15;
            float b = bo[col];
            #pragma unroll
            for (int reg = 0; reg < 4; ++reg) {
                int row = row0 + wm + mt * 16 + quad * 4 + reg;
                out[(size_t)row * D_MODEL + col] = acc[mt][nt][reg] + b;
            }
        }
    }
}

// ---------------------------------------------------------------------------
extern "C" void kernel_launch(void* const* d_in, const int* in_sizes, int n_in,
                              void* d_out, int out_size, void* d_ws, size_t ws_size,
                              hipStream_t stream)
{
    const float* q  = (const float*)d_in[0];
    const float* k  = (const float*)d_in[1];
    const float* v  = (const float*)d_in[2];
    const float* Wq = (const float*)d_in[3];
    const float* bq = (const float*)d_in[4];
    const float* Wk = (const float*)d_in[5];
    const float* bk = (const float*)d_in[6];
    const float* Wv = (const float*)d_in[7];
    const float* bv = (const float*)d_in[8];
    const float* Wo = (const float*)d_in[9];
    const float* bo = (const float*)d_in[10];
    float* out = (float*)d_out;

    const size_t SD = (size_t)S_LEN * D_MODEL;
    const size_t DD = (size_t)D_MODEL * D_MODEL;
    f16* base   = (f16*)d_ws;
    f16* WtBase = base;                  // Wtq|Wtk|Wtv|Wto (4*DD)
    f16* Wto    = WtBase + 3 * DD;
    f16* Qp     = base + 4 * DD;
    f16* Kp     = Qp + SD;
    f16* Vpt    = Kp + SD;               // [D][S]
    f16* qh     = Vpt + SD;              // 3SD region, reused after qkv_gemm:
    f16* kh     = qh + SD;
    f16* vh     = kh + SD;
    f16* Opart  = qh;                    //   2*SD (aliases qh,kh)
    f16* Ctx    = qh + 2 * SD;           //   1*SD (aliases vh)
    float* lsum = (float*)(base + 4 * DD + 6 * SD);  // [2][H][S]

    prep_kernel<<<3 * 1536 + 4 * 144, 256, 0, stream>>>(
        q, k, v, qh, kh, vh, Wq, Wk, Wv, Wo, WtBase);

    qkv_gemm_kernel<<<3 * 192, 256, 0, stream>>>(
        qh, kh, vh, WtBase, bq, bk, bv, Qp, Kp, Vpt);

    dim3 gAttn(S_LEN / 128, N_HEADS, SEG);   // (32, 12, 2)
    flash_attn_part_kernel<<<gAttn, 256, 0, stream>>>(Qp, Kp, Vpt, Opart, lsum);

    combine_kernel<<<1536, 256, 0, stream>>>(Opart, lsum, Ctx);

    oproj_kernel<<<192, 256, 0, stream>>>(Ctx, Wto, bo, out);
}